// Round 1
// baseline (85.988 us; speedup 1.0000x reference)
//
#include <hip/hip_runtime.h>
#include <cstddef>

#define T_DIM 30000
#define NSYN  1500
#define M_DIM 23
#define NJ    92      // 23*4 CRT classes
#define PADH  50
#define TILE  64      // output timesteps per block (kernel C)
#define NROW  168     // staged rows: TILE + 104 halo (rounded for 8-blocking)
#define PITCH 93      // LDS row pitch (pad +1)
#define WKP   120     // padded weight-kernel length: hp = h + 7, h in [-7,112]

// ---------------- Kernel B: X (T,1500) -> Y (T,92), Y[t,j] = sum_{n%92==j} X[t,n]
__global__ __launch_bounds__(256) void reduce_k(const float* __restrict__ X,
                                                float* __restrict__ Y) {
    int idx = blockIdx.x * 256 + threadIdx.x;
    if (idx >= T_DIM * 23) return;
    int t = idx / 23;
    int q = idx - t * 23;                       // float4 column class 0..22
    const float4* Xr = reinterpret_cast<const float4*>(X) + (size_t)t * 375;
    float4 s = make_float4(0.f, 0.f, 0.f, 0.f);
    int kc = (q < 7) ? 17 : 16;                 // 7*17 + 16*16 = 375
    for (int k = 0; k < kc; ++k) {
        float4 v = Xr[q + 23 * k];
        s.x += v.x; s.y += v.y; s.z += v.z; s.w += v.w;
    }
    reinterpret_cast<float4*>(Y)[(size_t)t * 23 + q] = s;
}

// ---------------- Kernel C: conv over time (92 chans, 4 kernels) + tree cascade
__global__ __launch_bounds__(192) void conv_tree_k(
    const float* __restrict__ Y,
    const float* __restrict__ Vo,
    const float* __restrict__ Tau,
    const float* __restrict__ Delta,
    const float* __restrict__ W,
    const float* __restrict__ C,
    const float* __restrict__ Theta,
    float* __restrict__ out)
{
    __shared__ float Yt[NROW * PITCH];   // 62496 B; reused as sub[64][24] later
    __shared__ float wkp[4 * WKP];       // zero-padded weighted kernels
    __shared__ float sTheta[M_DIM];
    __shared__ float sExpC[M_DIM];

    const int tid = threadIdx.x;
    const int t0  = blockIdx.x * TILE;

    // --- stage weighted group kernels (with zero pad outside h in [0,100])
    float eD = __expf(Delta[0]);
    for (int i = tid; i < 4 * WKP; i += 192) {
        int g = i / WKP, hp = i - g * WKP;
        int h = hp - 7;
        float val = 0.f;
        if (h >= 0 && h <= 100) {
            float tt  = fmaxf((float)h - eD, 0.f);
            float tau = __expf(Tau[g]);
            float tf  = tt / tau;
            float fast = tf * __expf(-tf);
            float kv;
            if (g < 2) {
                float ts   = tt / (tau * 2.8f + 10.4f);
                float slow = ts * __expf(-ts) * 0.3f;
                kv = (fast + slow) * (1.0f / 1.3f);
            } else {
                kv = fast;
            }
            val = kv * W[g];
        }
        wkp[i] = val;
    }
    if (tid < M_DIM) {
        sTheta[tid] = Theta[tid];
        sExpC[tid]  = __expf(C[tid]);
    }

    // --- stage Y tile rows [t0-50, t0+117], columns permuted: c' = (c>>2) + 23*(c&3)
    // (groups the j ≡ g (mod 4) classes into contiguous 23-column blocks -> no
    //  systematic mod-4 bank aliasing in the compute phase)
    for (int i = tid; i < NROW * NJ; i += 192) {
        int r  = i / NJ;
        int cp = i - r * NJ;                 // permuted column (matches LDS addr)
        int g2 = cp / 23;
        int b  = cp - g2 * 23;
        int c  = 4 * b + g2;                 // original column
        int grow = t0 + r - PADH;
        float v = 0.f;
        if (grow >= 0 && grow < T_DIM) v = Y[(size_t)grow * NJ + c];
        Yt[r * PITCH + cp] = v;
    }
    __syncthreads();

    // --- compute: 184 threads = 23 m-values x 8 t-subblocks of 8
    float acc[8];
    int m = 0, i8 = 0;
    if (tid < 184) {
        m  = tid % 23;
        i8 = tid / 23;
        // permuted LDS column for (m, g):  j = m + 23a with j%4 == g  ->  col' = (j>>2) + 23g
        int jcol[4];
        #pragma unroll
        for (int a = 0; a < 4; ++a) {
            int j = m + 23 * a;
            int g = j & 3;
            jcol[g] = (j >> 2) + 23 * g;
        }
        #pragma unroll
        for (int r = 0; r < 8; ++r) acc[r] = 0.f;

        const int base = i8 * 8;
        for (int rb = 0; rb < 112; rb += 8) {
            #pragma unroll
            for (int g = 0; g < 4; ++g) {
                float v[8];
                #pragma unroll
                for (int k = 0; k < 8; ++k)
                    v[k] = Yt[(base + rb + k) * PITCH + jcol[g]];
                float wv[15];
                #pragma unroll
                for (int k = 0; k < 15; ++k)
                    wv[k] = wkp[g * WKP + rb + k];
                // acc[r] (output t = t0+base+r) gets row L=base+rb+k with
                // h = (L-50) - (base+r) + 50 = rb+k-r ; wkp idx = h+7 = rb + (k-r+7)
                #pragma unroll
                for (int k = 0; k < 8; ++k) {
                    #pragma unroll
                    for (int r = 0; r < 8; ++r)
                        acc[r] += v[k] * wv[k - r + 7];
                }
            }
        }
    }
    __syncthreads();   // done reading Yt; safe to overwrite with sub_in

    if (tid < 184) {
        #pragma unroll
        for (int r = 0; r < 8; ++r)
            Yt[(i8 * 8 + r) * 24 + m] = acc[r];
    }
    __syncthreads();

    // --- tree cascade, one thread per timestep
    if (tid < TILE) {
        int t = t0 + tid;
        if (t < T_DIM) {
            const float* s = &Yt[tid * 24];
            float o[M_DIM];
            #pragma unroll
            for (int mm = 11; mm < 23; ++mm) {
                float x = s[mm] - sTheta[mm];
                o[mm] = sExpC[mm] / (1.f + __expf(-x));
            }
            #pragma unroll
            for (int r = 10; r >= 0; --r) {
                float x = s[r] + o[2 * r + 1] + o[2 * r + 2] - sTheta[r];
                o[r] = sExpC[r] / (1.f + __expf(-x));
            }
            out[t] = o[0] + Vo[0];
        }
    }
}

extern "C" void kernel_launch(void* const* d_in, const int* in_sizes, int n_in,
                              void* d_out, int out_size, void* d_ws, size_t ws_size,
                              hipStream_t stream) {
    const float* X     = (const float*)d_in[0];
    const float* Vo    = (const float*)d_in[1];
    const float* Tau   = (const float*)d_in[2];
    const float* Delta = (const float*)d_in[3];
    const float* W     = (const float*)d_in[4];
    const float* C     = (const float*)d_in[5];
    const float* Theta = (const float*)d_in[6];
    float* out = (float*)d_out;
    float* Yw  = (float*)d_ws;   // T_DIM * 92 floats = 11.04 MB

    int totalB = T_DIM * 23;
    reduce_k<<<(totalB + 255) / 256, 256, 0, stream>>>(X, Yw);
    conv_tree_k<<<(T_DIM + TILE - 1) / TILE, 192, 0, stream>>>(
        Yw, Vo, Tau, Delta, W, C, Theta, out);
}

// Round 2
// 59.110 us; speedup vs baseline: 1.4547x; 1.4547x over previous
//
#include <hip/hip_runtime.h>
#include <cstddef>

#define T_DIM 30000
#define M_DIM 23
#define NJ    92
#define PADH  50
#define TILE  64      // output timesteps per conv block
#define NROWW 168     // staged t' rows (need 165, padded to 168 = 84 pairs)
#define STR   184     // Yt stride in bf16 units (368 B, multiple of 16 B)
#define WKP   128     // padded weight length, index = h + 7, h in [0,100]

__device__ __forceinline__ unsigned short f2bf(float f) {
    unsigned int u = __float_as_uint(f);
    return (unsigned short)((u + 0x7fffu + ((u >> 16) & 1u)) >> 16);
}
__device__ __forceinline__ float bflo(unsigned int u) { return __uint_as_float(u << 16); }
__device__ __forceinline__ float bfhi(unsigned int u) { return __uint_as_float(u & 0xffff0000u); }

// ---- Kernel B: X (T,1500) fp32 -> Yb (T,92) bf16 ; Yb[t,j] = sum_{n%92==j} X[t,n]
__global__ __launch_bounds__(256) void reduce_k(const float* __restrict__ X,
                                                unsigned short* __restrict__ Yb) {
    int idx = blockIdx.x * 256 + threadIdx.x;
    if (idx >= T_DIM * 23) return;
    int t = idx / 23;
    int q = idx - t * 23;                     // float4-column class 0..22
    const float4* Xr = reinterpret_cast<const float4*>(X) + (size_t)t * 375;
    float4 s = make_float4(0.f, 0.f, 0.f, 0.f);
    int kc = (q < 7) ? 17 : 16;               // 7*17 + 16*16 = 375
    for (int k = 0; k < kc; ++k) {
        float4 v = Xr[q + 23 * k];
        s.x += v.x; s.y += v.y; s.z += v.z; s.w += v.w;
    }
    ushort4 o;
    o.x = f2bf(s.x); o.y = f2bf(s.y); o.z = f2bf(s.z); o.w = f2bf(s.w);
    reinterpret_cast<ushort4*>(Yb)[(size_t)t * 23 + q] = o;
}

// ---- Kernel C: depthwise temporal conv (92 chans, 4 kernels) + tree cascade
__global__ __launch_bounds__(192) void conv_tree_k(
    const unsigned short* __restrict__ Yb,
    const float* __restrict__ Vo,
    const float* __restrict__ Tau,
    const float* __restrict__ Delta,
    const float* __restrict__ W,
    const float* __restrict__ C,
    const float* __restrict__ Theta,
    float* __restrict__ out)
{
    __shared__ __align__(16) unsigned short Yt[NJ * STR];  // col-major bf16, 33.9 KB
    __shared__ __align__(16) float wkp2[4 * WKP];          // zero-padded weights, 2 KB
    __shared__ float sub[TILE * 24];                       // sub_in staging, 6.1 KB
    __shared__ float sTheta[M_DIM];
    __shared__ float sExpC[M_DIM];

    const int tid = threadIdx.x;
    const int t0  = blockIdx.x * TILE;

    // --- weights: wkp2[g][i] = wk(g, h=i-7) * W[g], zero outside h in [0,100]
    float eD = __expf(Delta[0]);
    for (int i = tid; i < 4 * WKP; i += 192) {
        int g = i >> 7, hp = i & 127;
        int h = hp - 7;
        float val = 0.f;
        if (h >= 0 && h <= 100) {
            float tt  = fmaxf((float)h - eD, 0.f);
            float tau = __expf(Tau[g]);
            float tf  = tt / tau;
            float fast = tf * __expf(-tf);
            float kv;
            if (g < 2) {
                float ts   = tt / (tau * 2.8f + 10.4f);
                float slow = ts * __expf(-ts) * 0.3f;
                kv = (fast + slow) * (1.0f / 1.3f);
            } else {
                kv = fast;
            }
            val = kv * W[g];
        }
        wkp2[i] = val;
    }
    if (tid < M_DIM) {
        sTheta[tid] = Theta[tid];
        sExpC[tid]  = __expf(C[tid]);
    }

    // --- stage Yb rows [t0-50, t0+118) transposed into Yt[col'][t'] (bf16),
    //     col' = (c>>2) + 23*(c&3). Row pairs -> packed dword writes.
    {
        unsigned int* Yw = reinterpret_cast<unsigned int*>(Yt);
        for (int i = tid; i < 84 * 23; i += 192) {
            int rp = i / 23;
            int q  = i - rp * 23;
            int g0 = t0 - PADH + 2 * rp;
            ushort4 ra = make_ushort4(0, 0, 0, 0);
            ushort4 rb = make_ushort4(0, 0, 0, 0);
            if ((unsigned)g0       < (unsigned)T_DIM) ra = reinterpret_cast<const ushort4*>(Yb)[(size_t)g0 * 23 + q];
            if ((unsigned)(g0 + 1) < (unsigned)T_DIM) rb = reinterpret_cast<const ushort4*>(Yb)[(size_t)(g0 + 1) * 23 + q];
            // dword index = col' * (STR/2) + rp ; pack (even row lo, odd row hi)
            Yw[(q     ) * 92 + rp] = (unsigned)ra.x | ((unsigned)rb.x << 16);
            Yw[(q + 23) * 92 + rp] = (unsigned)ra.y | ((unsigned)rb.y << 16);
            Yw[(q + 46) * 92 + rp] = (unsigned)ra.z | ((unsigned)rb.z << 16);
            Yw[(q + 69) * 92 + rp] = (unsigned)ra.w | ((unsigned)rb.w << 16);
        }
    }
    __syncthreads();

    // --- compute: 184 threads = 23 m x 8 t-subblocks of 8 outputs
    int m = 0, i8 = 0;
    float acc[8];
    if (tid < 184) {
        m  = tid % 23;
        i8 = tid / 23;
        int jcol[4];
        #pragma unroll
        for (int a = 0; a < 4; ++a) {
            int j = m + 23 * a;
            int g = j & 3;
            jcol[g] = (j >> 2) + 23 * g;      // permuted column for (m,g)
        }
        #pragma unroll
        for (int r = 0; r < 8; ++r) acc[r] = 0.f;

        const int base = i8 * 8;
        for (int rb = 0; rb < 112; rb += 8) {
            #pragma unroll
            for (int g = 0; g < 4; ++g) {
                uint4 vv = *reinterpret_cast<const uint4*>(&Yt[jcol[g] * STR + base + rb]);
                float v[8];
                v[0] = bflo(vv.x); v[1] = bfhi(vv.x);
                v[2] = bflo(vv.y); v[3] = bfhi(vv.y);
                v[4] = bflo(vv.z); v[5] = bfhi(vv.z);
                v[6] = bflo(vv.w); v[7] = bfhi(vv.w);
                const float4* wp = reinterpret_cast<const float4*>(&wkp2[g * WKP + rb]);
                float4 w0 = wp[0], w1 = wp[1], w2 = wp[2], w3 = wp[3];
                float wf[16] = { w0.x, w0.y, w0.z, w0.w, w1.x, w1.y, w1.z, w1.w,
                                 w2.x, w2.y, w2.z, w2.w, w3.x, w3.y, w3.z, w3.w };
                // acc[r] (output t0+base+r) += row(base+rb+k) * wk[h = rb+k-r]
                #pragma unroll
                for (int k = 0; k < 8; ++k) {
                    #pragma unroll
                    for (int r = 0; r < 8; ++r)
                        acc[r] += v[k] * wf[k - r + 7];
                }
            }
        }
        #pragma unroll
        for (int r = 0; r < 8; ++r)
            sub[(base + r) * 24 + m] = acc[r];
    }
    __syncthreads();

    // --- tree cascade, one thread per timestep
    if (tid < TILE) {
        int t = t0 + tid;
        if (t < T_DIM) {
            const float* s = &sub[tid * 24];
            float o[M_DIM];
            #pragma unroll
            for (int mm = 11; mm < 23; ++mm) {
                float x = s[mm] - sTheta[mm];
                o[mm] = sExpC[mm] / (1.f + __expf(-x));
            }
            #pragma unroll
            for (int r = 10; r >= 0; --r) {
                float x = s[r] + o[2 * r + 1] + o[2 * r + 2] - sTheta[r];
                o[r] = sExpC[r] / (1.f + __expf(-x));
            }
            out[t] = o[0] + Vo[0];
        }
    }
}

extern "C" void kernel_launch(void* const* d_in, const int* in_sizes, int n_in,
                              void* d_out, int out_size, void* d_ws, size_t ws_size,
                              hipStream_t stream) {
    const float* X     = (const float*)d_in[0];
    const float* Vo    = (const float*)d_in[1];
    const float* Tau   = (const float*)d_in[2];
    const float* Delta = (const float*)d_in[3];
    const float* W     = (const float*)d_in[4];
    const float* C     = (const float*)d_in[5];
    const float* Theta = (const float*)d_in[6];
    float* out = (float*)d_out;
    unsigned short* Yb = (unsigned short*)d_ws;   // T_DIM * 92 bf16 = 5.52 MB

    reduce_k<<<(T_DIM * 23 + 255) / 256, 256, 0, stream>>>(X, Yb);
    conv_tree_k<<<(T_DIM + TILE - 1) / TILE, 192, 0, stream>>>(
        Yb, Vo, Tau, Delta, W, C, Theta, out);
}